// Round 18
// baseline (838.326 us; speedup 1.0000x reference)
//
#include <hip/hip_runtime.h>
#include <stdint.h>

#define DEV static __device__ __forceinline__

typedef float f32x4 __attribute__((ext_vector_type(4)));
typedef short s16x8 __attribute__((ext_vector_type(8)));
typedef unsigned short u16;

constexpr int D   = 512;
constexpr int H   = 8;
constexpr int DHd = 64;
constexpr int S   = 1024;
constexpr int Bn  = 8;
constexpr int L   = 6;
constexpr int FF  = 2048;
constexpr int TOK = Bn * S;   // 8192
constexpr int QKV = 3 * D;    // 1536
constexpr int KVB = 64;       // attention key/value tile

// ---------- helpers ----------
DEV u16 f2bf(float f) {
  union { float f; uint32_t u; } v; v.f = f;
  uint32_t u = v.u;
  u += 0x7FFFu + ((u >> 16) & 1u);   // RNE
  return (u16)(u >> 16);
}

// hw packed f32x2 -> bf16x2 (lo = a, hi = b); single VALU op
DEV uint32_t cvtpk(float a, float b) {
  uint32_t r;
  asm("v_cvt_pk_bf16_f32 %0, %1, %2" : "=v"(r) : "v"(a), "v"(b));
  return r;
}

DEV float bf2f(u16 u) {
  union { uint32_t u; float f; } t;
  t.u = ((uint32_t)u) << 16;
  return t.f;
}

DEV f32x4 mfma16(s16x8 a, s16x8 b, f32x4 c) {
  return __builtin_amdgcn_mfma_f32_16x16x32_bf16(a, b, c, 0, 0, 0);
}

typedef __attribute__((address_space(1))) const void GV;
typedef __attribute__((address_space(3))) void LV;
DEV void gload_lds16(const u16* g, u16* l) {
  __builtin_amdgcn_global_load_lds((GV*)g, (LV*)l, 16, 0, 0);
}

// ---------- weight transpose: 4 D x D matrices per layer in one dispatch ----------
__global__ __launch_bounds__(256) void wprep4_kernel(const float* __restrict__ wq,
                                                     const float* __restrict__ wk,
                                                     const float* __restrict__ wv,
                                                     const float* __restrict__ wo,
                                                     u16* __restrict__ wqkvT,
                                                     u16* __restrict__ woT) {
  __shared__ float tile[32][33];
  const int z = blockIdx.z, which = z & 3, lyr = z >> 2;
  const float* in = (which == 0 ? wq : which == 1 ? wk : which == 2 ? wv : wo)
                    + (size_t)lyr * D * D;
  u16* out = (which < 3) ? wqkvT + (size_t)lyr * QKV * D + (size_t)which * D * D
                         : woT + (size_t)lyr * D * D;
  const int k0 = blockIdx.x * 32, n0 = blockIdx.y * 32;
  const int tx = (int)threadIdx.x & 31, ty = (int)threadIdx.x >> 5;
#pragma unroll
  for (int i = 0; i < 32; i += 8)
    tile[ty + i][tx] = in[(size_t)(k0 + ty + i) * D + n0 + tx];
  __syncthreads();
#pragma unroll
  for (int i = 0; i < 32; i += 8)
    out[(size_t)(n0 + ty + i) * D + k0 + tx] = f2bf(tile[tx][ty + i]);
}

// ---------- generic weight transpose: f32 [K,N] -> bf16 [N,K], grid.z = layer ----------
__global__ __launch_bounds__(256) void wprep_kernel(const float* __restrict__ in,
                                                    u16* __restrict__ out, int K, int N,
                                                    size_t ostride) {
  __shared__ float tile[32][33];
  const int zl = blockIdx.z;
  in  += (size_t)zl * K * N;
  out += (size_t)zl * ostride;
  const int k0 = blockIdx.x * 32, n0 = blockIdx.y * 32;
  const int tx = (int)threadIdx.x & 31, ty = (int)threadIdx.x >> 5;
#pragma unroll
  for (int i = 0; i < 32; i += 8)
    tile[ty + i][tx] = in[(size_t)(k0 + ty + i) * N + n0 + tx];
  __syncthreads();
#pragma unroll
  for (int i = 0; i < 32; i += 8)
    out[(size_t)(n0 + ty + i) * K + k0 + tx] = f2bf(tile[tx][ty + i]);
}

// ---------- merged small prep: bias concat | mask bias | mask flags ----------
__global__ __launch_bounds__(256) void prep_kernel(const float* __restrict__ bq,
                                                   const float* __restrict__ bk,
                                                   const float* __restrict__ bv,
                                                   const int* __restrict__ mask,
                                                   float* __restrict__ bqkv,
                                                   float* __restrict__ mb,
                                                   int* __restrict__ flags) {
  const int blk = (int)blockIdx.x;
  const int tid = (int)threadIdx.x;
  if (blk < 36) {                       // bcat: L*QKV = 9216 elements
    const int i = blk * 256 + tid;
    const int l = i / QKV, r = i % QKV;
    const float* src = (r < D) ? bq : (r < 2 * D ? bk : bv);
    bqkv[i] = src[l * D + (r & (D - 1))];
  } else if (blk < 68) {                // mbias: TOK elements
    const int i = (blk - 36) * 256 + tid;
    mb[i] = (mask[i] == 0) ? -3e38f : 0.f;
  } else if (tid < 128) {               // mflag: 128 tiles of 64 keys
    const int* m = mask + (tid >> 4) * S + (tid & 15) * 64;
    int all = 1;
#pragma unroll
    for (int j = 0; j < 64; ++j) all &= (m[j] != 0) ? 1 : 0;
    flags[tid] = all;
  }
}

// ---------- embedding + positional encoding -> bf16 (4 tokens/block) ----------
__global__ __launch_bounds__(256) void embed_kernel(const int* __restrict__ src,
                                                    const float* __restrict__ emb,
                                                    const float* __restrict__ pe,
                                                    u16* __restrict__ xb) {
  const int t = (int)blockIdx.x * 4 + ((int)threadIdx.x >> 6);
  const int c = ((int)threadIdx.x & 63) * 8;
  const int s = t & (S - 1);
  const int tok = src[t];
  const float* ep = emb + (size_t)tok * D + c;
  const float* pp = pe + (size_t)s * D + c;
  const f32x4 e0 = *(const f32x4*)ep,       e1 = *(const f32x4*)(ep + 4);
  const f32x4 p0 = *(const f32x4*)pp,       p1 = *(const f32x4*)(pp + 4);
  uint4 ob;
  ob.x = cvtpk(e0[0] + p0[0], e0[1] + p0[1]);
  ob.y = cvtpk(e0[2] + p0[2], e0[3] + p0[3]);
  ob.z = cvtpk(e1[0] + p1[0], e1[1] + p1[1]);
  ob.w = cvtpk(e1[2] + p1[2], e1[3] + p1[3]);
  *(uint4*)(xb + (size_t)t * D + c) = ob;
}

// ---------- GEMM: C[M,N] = A[M,K](bf16) @ BT[N,K](bf16)^T ----------
// T3+T4 pipelined double-buffer: stage(t+1) issued before compute(t), with
// COUNTED s_waitcnt vmcnt(6) (tile t's 6 loads done; t+1's stay in flight
// across both raw s_barriers). This is the piece __syncthreads destroyed in
// r5/r7 (it drains vmcnt to 0). T2 source-swizzle conflict fix retained.
// KSPLIT>1: bf16 partials. VMODE: V cols transposed to outV; Q pre-scaled.
template <int MT, int VMODE, int KSPLIT>
__global__ __launch_bounds__(256) void gemm_kernel(const u16* __restrict__ A,
                                                   const u16* __restrict__ BT,
                                                   const float* __restrict__ bias,
                                                   u16* __restrict__ outB,
                                                   u16* __restrict__ outV,
                                                   int N, int K, int relu) {
  static_assert(MT == 2, "vmcnt count hard-coded for MT=2 (6 loads/thread)");
  constexpr int BM = MT * 32;
  constexpr float QSCL = 0.125f * 1.44269504089f;
  __shared__ u16 sA[2 * BM * 64];
  __shared__ u16 sB[2 * 128 * 64];
  const int tid = (int)threadIdx.x;
  const int w = tid >> 6, l = tid & 63;
  const int wr = w >> 1, wc = w & 1;
  const int lr = l & 15, lg = l >> 4;

  const int nwg = (int)gridDim.x;
  const int bid = (int)blockIdx.x;
  const int wg  = (bid & 7) * (nwg >> 3) + (bid >> 3);
  const int nbn = N >> 7;
  int kidx = 0, rem = wg;
  if constexpr (KSPLIT > 1) {
    const int per = nwg / KSPLIT;
    kidx = wg / per;
    rem  = wg % per;
  }
  const int bm = (rem / nbn) * BM, bn = (rem % nbn) * 128;
  const int KS = K / KSPLIT;

  f32x4 acc[MT][4];
#pragma unroll
  for (int i = 0; i < MT; ++i)
#pragma unroll
    for (int j = 0; j < 4; ++j)
#pragma unroll
      for (int r = 0; r < 4; ++r) acc[i][j][r] = 0.f;

  const int srow = tid >> 3;                       // 0..31
  const int sswz = ((tid & 7) ^ (srow & 7)) * 8;   // swizzled SOURCE chunk
  const int sdst = (tid & 7) * 8;                  // linear DEST chunk
  const u16* Ag = A + (size_t)(bm + srow) * K + kidx * KS + sswz;
  const u16* Bg = BT + (size_t)(bn + srow) * K + kidx * KS + sswz;

  auto stage = [&](int kt, int buf) {
    u16* ad = sA + buf * BM * 64 + srow * 64 + sdst;
    u16* bd = sB + buf * 128 * 64 + srow * 64 + sdst;
#pragma unroll
    for (int r = 0; r < BM / 32; ++r)
      gload_lds16(Ag + (size_t)(r * 32) * K + kt, ad + r * 32 * 64);
#pragma unroll
    for (int r = 0; r < 4; ++r)
      gload_lds16(Bg + (size_t)(r * 32) * K + kt, bd + r * 32 * 64);
  };
  auto compute = [&](int buf) {
    const u16* a0 = sA + buf * BM * 64;
    const u16* b0 = sB + buf * 128 * 64;
#pragma unroll
    for (int kk = 0; kk < 2; ++kk) {
      s16x8 af[MT], bfr[4];
      const int csw = ((kk * 4 + lg) ^ (lr & 7)) << 3;   // swizzled read chunk
#pragma unroll
      for (int mt = 0; mt < MT; ++mt)
        af[mt] = *(const s16x8*)&a0[(wr * MT * 16 + mt * 16 + lr) * 64 + csw];
#pragma unroll
      for (int nt = 0; nt < 4; ++nt)
        bfr[nt] = *(const s16x8*)&b0[(wc * 64 + nt * 16 + lr) * 64 + csw];
#pragma unroll
      for (int mt = 0; mt < MT; ++mt)
#pragma unroll
        for (int nt = 0; nt < 4; ++nt)
          acc[mt][nt] = mfma16(af[mt], bfr[nt], acc[mt][nt]);
    }
  };

  stage(0, 0);
  const int NT = KS >> 6;
  int cur = 0;
  for (int t = 0; t < NT - 1; ++t) {
    __builtin_amdgcn_s_barrier();             // all waves done reading buf[cur^1]
    stage((t + 1) * 64, cur ^ 1);             // prefetch stays in flight past barrier
    asm volatile("s_waitcnt vmcnt(6)" ::: "memory");   // tile t landed; t+1 in flight
    __builtin_amdgcn_sched_barrier(0);
    __builtin_amdgcn_s_barrier();
    __builtin_amdgcn_sched_barrier(0);
    compute(cur);
    cur ^= 1;
  }
  asm volatile("s_waitcnt vmcnt(0)" ::: "memory");
  __builtin_amdgcn_sched_barrier(0);
  __builtin_amdgcn_s_barrier();
  __builtin_amdgcn_sched_barrier(0);
  compute(cur);

#pragma unroll
  for (int mt = 0; mt < MT; ++mt)
#pragma unroll
    for (int nt = 0; nt < 4; ++nt) {
      const int col = bn + wc * 64 + nt * 16 + lr;
      const int row0 = bm + wr * MT * 16 + mt * 16 + lg * 4;
      if constexpr (KSPLIT > 1) {
        u16* op = outB + (size_t)kidx * TOK * N + (size_t)row0 * N + col;
        const uint32_t p01 = cvtpk(acc[mt][nt][0], acc[mt][nt][1]);
        const uint32_t p23 = cvtpk(acc[mt][nt][2], acc[mt][nt][3]);
        op[0]               = (u16)p01;
        op[N]               = (u16)(p01 >> 16);
        op[2 * (size_t)N]   = (u16)p23;
        op[3 * (size_t)N]   = (u16)(p23 >> 16);
      } else {
        const float bv = bias ? bias[col] : 0.f;
        if (VMODE && col >= 2 * D) {    // V projection -> transposed [B,H,DH,S]
          const int dcol = col - 2 * D;
          const int hh = dcol >> 6, dh = dcol & 63;
          const int bb = row0 >> 10, s = row0 & (S - 1);
          u16* vp = outV + ((size_t)((bb << 3) + hh) * DHd + dh) * S + s;
          *(uint32_t*)(vp)     = cvtpk(acc[mt][nt][0] + bv, acc[mt][nt][1] + bv);
          *(uint32_t*)(vp + 2) = cvtpk(acc[mt][nt][2] + bv, acc[mt][nt][3] + bv);
        } else {
          float v[4];
#pragma unroll
          for (int r = 0; r < 4; ++r) {
            v[r] = acc[mt][nt][r] + bv;
            if (relu) v[r] = fmaxf(v[r], 0.f);
            if (VMODE && col < D) v[r] *= QSCL;
          }
          const size_t o0 = (size_t)row0 * N + col;
          const uint32_t p01 = cvtpk(v[0], v[1]);
          const uint32_t p23 = cvtpk(v[2], v[3]);
          outB[o0]                   = (u16)p01;
          outB[o0 + N]               = (u16)(p01 >> 16);
          outB[o0 + 2 * (size_t)N]   = (u16)p23;
          outB[o0 + 3 * (size_t)N]   = (u16)(p23 >> 16);
        }
      }
    }
}

// ---------- flash attention v9: 8 waves x 32 q, dbuf K/V, dual P slabs, no max ----------
__global__ __launch_bounds__(512) void attn_kernel(const u16* __restrict__ qkv,
                                                   const u16* __restrict__ vt,
                                                   const int* __restrict__ mflags,
                                                   const float* __restrict__ mb,
                                                   u16* __restrict__ attno) {
  __shared__ u16 sK[2][KVB * 72];
  __shared__ u16 sV[2][KVB * 72];
  __shared__ u16 sP[8][2][16][72];   // per-wave, per-q-frag slab
  const int tid = (int)threadIdx.x;
  const int w = tid >> 6, l = tid & 63;
  const int lr = l & 15, lg = l >> 4;
  const int bid = (int)blockIdx.x;
  const int wg  = (bid & 7) * 32 + (bid >> 3);
  const int bh = wg >> 2, qc = wg & 3;
  const int b = bh >> 3, h = bh & 7;
  const int q0 = qc * 256 + w * 32;

  const u16* qr0 = qkv + (size_t)(b * S + q0 + lr) * QKV + h * DHd;
  const u16* qr1 = qr0 + (size_t)16 * QKV;
  const s16x8 aq0 = *(const s16x8*)(qr0 + lg * 8);
  const s16x8 aq1 = *(const s16x8*)(qr0 + 32 + lg * 8);
  const s16x8 aq2 = *(const s16x8*)(qr1 + lg * 8);
  const s16x8 aq3 = *(const s16x8*)(qr1 + 32 + lg * 8);
  const u16* kbase = qkv + D + (size_t)b * S * QKV + h * DHd;
  const u16* vbase = vt + (size_t)bh * DHd * S;
  const float* mrow0 = mb + b * S;

  s16x8 vones;
#pragma unroll
  for (int i = 0; i < 8; ++i) vones[i] = (short)0x3F80;   // bf16 1.0

  const int srow = tid >> 3;       // 0..63
  const int sc16 = tid & 7;        // 0..7
  const u16* kg = kbase + (size_t)srow * QKV + sc16 * 8;
  const u16* vg = vbase + (size_t)srow * S + sc16 * 8;
  const int soff = srow * 72 + sc16 * 8;

  // prologue: tile0 -> buf0; tile1 -> regs
  uint4 ka = *(const uint4*)kg;
  uint4 va = *(const uint4*)vg;
  *(uint4*)&sK[0][soff] = ka;
  *(uint4*)&sV[0][soff] = va;
  ka = *(const uint4*)(kg + (size_t)KVB * QKV);
  va = *(const uint4*)(vg + KVB);
  __syncthreads();

  f32x4 o[2][4], osum[2];
#pragma unroll
  for (int f = 0; f < 2; ++f) {
#pragma unroll
    for (int nt = 0; nt < 4; ++nt)
#pragma unroll
      for (int r = 0; r < 4; ++r) o[f][nt][r] = 0.f;
#pragma unroll
    for (int r = 0; r < 4; ++r) osum[f][r] = 0.f;
  }

  constexpr int NTILE = S / KVB;   // 16
  for (int t = 0; t < NTILE; ++t) {
    const int cur = t & 1;
    if (t + 1 < NTILE) {           // write staged tile t+1 (buffer t-1, reads done)
      *(uint4*)&sK[cur ^ 1][soff] = ka;
      *(uint4*)&sV[cur ^ 1][soff] = va;
    }
    if (t + 2 < NTILE) {           // issue loads for tile t+2
      ka = *(const uint4*)(kg + (size_t)(t + 2) * KVB * QKV);
      va = *(const uint4*)(vg + (t + 2) * KVB);
    }

    // swapped QK^T (Q pre-scaled -> log2-domain scores)
    f32x4 sa[2][4];
#pragma unroll
    for (int kt = 0; kt < 4; ++kt) {
      const u16* kr = &sK[cur][(kt * 16 + lr) * 72];
      const s16x8 bk0 = *(const s16x8*)(kr + lg * 8);
      const s16x8 bk1 = *(const s16x8*)(kr + 32 + lg * 8);
      f32x4 za, zb;
#pragma unroll
      for (int r = 0; r < 4; ++r) { za[r] = 0.f; zb[r] = 0.f; }
      za = mfma16(bk0, aq0, za);
      sa[0][kt] = mfma16(bk1, aq1, za);
      zb = mfma16(bk0, aq2, zb);
      sa[1][kt] = mfma16(bk1, aq3, zb);
    }

    if (!mflags[(b << 4) + t]) {   // mask add (skipped: all-valid tiles)
#pragma unroll
      for (int kt = 0; kt < 4; ++kt) {
        const f32x4 mk = *(const f32x4*)(mrow0 + t * KVB + kt * 16 + lg * 4);
#pragma unroll
        for (int r = 0; r < 4; ++r) {
          sa[0][kt][r] += mk[r];
          sa[1][kt][r] += mk[r];
        }
      }
    }

    // P = exp2(S) directly (no max); normalization cancels any shift
#pragma unroll
    for (int f = 0; f < 2; ++f)
#pragma unroll
      for (int kt = 0; kt < 4; ++kt)
#pragma unroll
        for (int r = 0; r < 4; ++r) sa[f][kt][r] = exp2f(sa[f][kt][r]);

    // pack both frags to their own slabs
#pragma unroll
    for (int f = 0; f < 2; ++f)
#pragma unroll
      for (int kt = 0; kt < 4; ++kt) {
        uint2 pk;
        pk.x = cvtpk(sa[f][kt][0], sa[f][kt][1]);
        pk.y = cvtpk(sa[f][kt][2], sa[f][kt][3]);
        *(uint2*)&sP[w][f][lr][kt * 16 + lg * 4] = pk;
      }

    // V fragments once, shared by both q-frags
    s16x8 bv[2][4];
#pragma unroll
    for (int ks = 0; ks < 2; ++ks)
#pragma unroll
      for (int nt = 0; nt < 4; ++nt)
        bv[ks][nt] = *(const s16x8*)&sV[cur][(nt * 16 + lr) * 72 + ks * 32 + lg * 8];

#pragma unroll
    for (int ks = 0; ks < 2; ++ks) {
      const s16x8 ap0 = *(const s16x8*)&sP[w][0][lr][ks * 32 + lg * 8];
      const s16x8 ap1 = *(const s16x8*)&sP[w][1][lr][ks * 32 + lg * 8];
      osum[0] = mfma16(ap0, vones, osum[0]);
      osum[1] = mfma16(ap1, vones, osum[1]);
#pragma unroll
      for (int nt = 0; nt < 4; ++nt) {
        o[0][nt] = mfma16(ap0, bv[ks][nt], o[0][nt]);
        o[1][nt] = mfma16(ap1, bv[ks][nt], o[1][nt]);
      }
    }
    __syncthreads();
  }

#pragma unroll
  for (int f = 0; f < 2; ++f) {
    float li[4];
#pragma unroll
    for (int r = 0; r < 4; ++r) li[r] = 1.f / osum[f][r];
#pragma unroll
    for (int nt = 0; nt < 4; ++nt) {
      u16* op = attno + (size_t)(b * S + q0 + f * 16 + lg * 4) * D + h * DHd + nt * 16 + lr;
#pragma unroll
      for (int r = 0; r < 4; r += 2) {
        const uint32_t pk = cvtpk(o[f][nt][r] * li[r], o[f][nt][r + 1] * li[r + 1]);
        op[(size_t)r * D]       = (u16)pk;
        op[(size_t)(r + 1) * D] = (u16)(pk >> 16);
      }
    }
  }
}

// ---------- LayerNorm over NP bf16 partials + bias + bf16 resid ----------
template <int NP>
__global__ __launch_bounds__(256) void ln_kernel(const u16* __restrict__ p,
                                                 const float* __restrict__ bias,
                                                 const u16* __restrict__ resid,
                                                 const float* __restrict__ g,
                                                 const float* __restrict__ be,
                                                 float* __restrict__ outf,   // nullable
                                                 u16* __restrict__ outb) {
  const int w = (int)threadIdx.x >> 6, l = (int)threadIdx.x & 63;
  const int t = (int)blockIdx.x * 4 + w;
  const size_t base = (size_t)t * D + l * 8;
  f32x4 v0 = *(const f32x4*)(bias + l * 8);
  f32x4 v1 = *(const f32x4*)(bias + l * 8 + 4);
  {
    const s16x8 rv = *(const s16x8*)(resid + base);
#pragma unroll
    for (int i = 0; i < 4; ++i) {
      v0[i] += bf2f((u16)rv[i]);
      v1[i] += bf2f((u16)rv[i + 4]);
    }
  }
#pragma unroll
  for (int np = 0; np < NP; ++np) {
    const s16x8 pv = *(const s16x8*)(p + (size_t)np * TOK * D + base);
#pragma unroll
    for (int i = 0; i < 4; ++i) {
      v0[i] += bf2f((u16)pv[i]);
      v1[i] += bf2f((u16)pv[i + 4]);
    }
  }
  float s = 0.f, sq = 0.f;
#pragma unroll
  for (int i = 0; i < 4; ++i) {
    s += v0[i] + v1[i];
    sq += v0[i] * v0[i] + v1[i] * v1[i];
  }
  for (int m = 1; m < 64; m <<= 1) {
    s += __shfl_xor(s, m);
    sq += __shfl_xor(sq, m);
  }
  const float mu = s * (1.0f / D);
  const float var = sq * (1.0f / D) - mu * mu;
  const float rs = rsqrtf(var + 1e-5f);
  const f32x4 g0 = *(const f32x4*)(g + l * 8);
  const f32x4 g1v = *(const f32x4*)(g + l * 8 + 4);
  const f32x4 b0 = *(const f32x4*)(be + l * 8);
  const f32x4 b1v = *(const f32x4*)(be + l * 8 + 4);
  f32x4 y0, y1;
#pragma unroll
  for (int i = 0; i < 4; ++i) {
    y0[i] = (v0[i] - mu) * rs * g0[i] + b0[i];
    y1[i] = (v1[i] - mu) * rs * g1v[i] + b1v[i];
  }
  uint4 ob;
  ob.x = cvtpk(y0[0], y0[1]);
  ob.y = cvtpk(y0[2], y0[3]);
  ob.z = cvtpk(y1[0], y1[1]);
  ob.w = cvtpk(y1[2], y1[3]);
  if (outf) {
    *(f32x4*)(outf + base) = y0;
    *(f32x4*)(outf + base + 4) = y1;
  }
  *(uint4*)(outb + base) = ob;
}

// ---------- launch ----------
extern "C" void kernel_launch(void* const* d_in, const int* in_sizes, int n_in,
                              void* d_out, int out_size, void* d_ws, size_t ws_size,
                              hipStream_t stream) {
  (void)in_sizes; (void)n_in; (void)out_size; (void)ws_size;
  const int*   src  = (const int*)d_in[0];
  const int*   mask = (const int*)d_in[1];
  const float* emb  = (const float*)d_in[2];
  const float* pe   = (const float*)d_in[3];
  const float* wq = (const float*)d_in[4];  const float* bq = (const float*)d_in[5];
  const float* wk = (const float*)d_in[6];  const float* bk = (const float*)d_in[7];
  const float* wv = (const float*)d_in[8];  const float* bv = (const float*)d_in[9];
  const float* wo = (const float*)d_in[10]; const float* bo = (const float*)d_in[11];
  const float* w1 = (const float*)d_in[12]; const float* b1 = (const float*)d_in[13];
  const float* w2 = (const float*)d_in[14]; const float* b2 = (const float*)d_in[15];
  const float* g1 = (const float*)d_in[16]; const float* be1 = (const float*)d_in[17];
  const float* g2 = (const float*)d_in[18]; const float* be2 = (const float*)d_in[19];

  char* ws = (char*)d_ws;
  size_t off = 0;
  auto alloc = [&](size_t bytes) -> void* {
    void* p = ws + off;
    off += (bytes + 255) & ~(size_t)255;
    return p;
  };

  u16* wqkvT = (u16*)alloc((size_t)L * QKV * D * 2);
  u16* woT   = (u16*)alloc((size_t)L * D * D * 2);
  u16* w1T   = (u16*)alloc((size_t)L * D * FF * 2);
  u16* w2T   = (u16*)alloc((size_t)L * D * FF * 2);
  float* bqkv = (float*)alloc((size_t)L * QKV * 4);
  float* mbf  = (float*)alloc((size_t)TOK * 4);
  int*   mflg = (int*)alloc(128 * 4);
  u16* xb    = (u16*)alloc((size_t)TOK * D * 2);   // residual / layer input (bf16)
  u16* x1b   = (u16*)alloc((size_t)TOK * D * 2);
  u16* attno = (u16*)alloc((size_t)TOK * D * 2);
  u16* qkvb  = (u16*)alloc((size_t)TOK * FF * 2);  // qkv | FFN hidden (aliased)
  u16* vtb   = (u16*)alloc((size_t)TOK * D * 2);
  u16* hbuf  = qkvb;
  u16* pf    = (u16*)alloc((size_t)2 * TOK * D * 2);  // split-K bf16 partials (NP=2)
  u16* po    = pf;

  const dim3 blk(256);

  wprep4_kernel<<<dim3(16, 16, 4 * L), blk, 0, stream>>>(wq, wk, wv, wo, wqkvT, woT);
  wprep_kernel<<<dim3(16, 64, L), blk, 0, stream>>>(w1, w1T, D, FF, (size_t)D * FF);
  wprep_kernel<<<dim3(64, 16, L), blk, 0, stream>>>(w2, w2T, FF, D, (size_t)D * FF);
  prep_kernel<<<dim3(69), blk, 0, stream>>>(bq, bk, bv, mask, bqkv, mbf, mflg);

  embed_kernel<<<TOK / 4, blk, 0, stream>>>(src, emb, pe, xb);

  for (int lyr = 0; lyr < L; ++lyr) {
    const size_t wOffQ = (size_t)lyr * QKV * D;
    const size_t wOffD = (size_t)lyr * D * D;
    const size_t wOffF = (size_t)lyr * D * FF;
    // fused QKV projection (BM=64); V transposed in-epilogue; Q pre-scaled
    gemm_kernel<2, 1, 1><<<dim3(128 * 12), blk, 0, stream>>>(xb, wqkvT + wOffQ, bqkv + lyr * QKV,
                                                             qkvb, vtb, QKV, D, 0);
    attn_kernel<<<dim3(256), dim3(512), 0, stream>>>(qkvb, vtb, mflg, mbf, attno);
    // O-projection: split-K=2 -> bf16 partials; bias+resid fused into LN1
    gemm_kernel<2, 0, 2><<<dim3(128 * 4 * 2), blk, 0, stream>>>(attno, woT + wOffD, nullptr,
                                                                po, nullptr, D, D, 0);
    ln_kernel<2><<<TOK / 4, blk, 0, stream>>>(po, bo + lyr * D, xb,
                                              g1 + lyr * D, be1 + lyr * D, nullptr, x1b);
    // FFN (BM=64)
    gemm_kernel<2, 0, 1><<<dim3(128 * 16), blk, 0, stream>>>(x1b, w1T + wOffF, b1 + lyr * FF,
                                                             hbuf, nullptr, FF, D, 1);
    gemm_kernel<2, 0, 2><<<dim3(128 * 4 * 2), blk, 0, stream>>>(hbuf, w2T + wOffF, nullptr,
                                                                pf, nullptr, D, FF, 0);
    float* xdst = (lyr == L - 1) ? (float*)d_out : nullptr;
    ln_kernel<2><<<TOK / 4, blk, 0, stream>>>(pf, b2 + lyr * D, x1b,
                                              g2 + lyr * D, be2 + lyr * D, xdst, xb);
  }
}

// Round 19
// 827.114 us; speedup vs baseline: 1.0136x; 1.0136x over previous
//
#include <hip/hip_runtime.h>
#include <stdint.h>

#define DEV static __device__ __forceinline__

typedef float f32x4 __attribute__((ext_vector_type(4)));
typedef short s16x8 __attribute__((ext_vector_type(8)));
typedef unsigned short u16;

constexpr int D   = 512;
constexpr int H   = 8;
constexpr int DHd = 64;
constexpr int S   = 1024;
constexpr int Bn  = 8;
constexpr int L   = 6;
constexpr int FF  = 2048;
constexpr int TOK = Bn * S;   // 8192
constexpr int QKV = 3 * D;    // 1536
constexpr int KVB = 64;       // attention key/value tile

// ---------- helpers ----------
DEV u16 f2bf(float f) {
  union { float f; uint32_t u; } v; v.f = f;
  uint32_t u = v.u;
  u += 0x7FFFu + ((u >> 16) & 1u);   // RNE
  return (u16)(u >> 16);
}

// hw packed f32x2 -> bf16x2 (lo = a, hi = b); single VALU op
DEV uint32_t cvtpk(float a, float b) {
  uint32_t r;
  asm("v_cvt_pk_bf16_f32 %0, %1, %2" : "=v"(r) : "v"(a), "v"(b));
  return r;
}

DEV float bf2f(u16 u) {
  union { uint32_t u; float f; } t;
  t.u = ((uint32_t)u) << 16;
  return t.f;
}

DEV f32x4 mfma16(s16x8 a, s16x8 b, f32x4 c) {
  return __builtin_amdgcn_mfma_f32_16x16x32_bf16(a, b, c, 0, 0, 0);
}

typedef __attribute__((address_space(1))) const void GV;
typedef __attribute__((address_space(3))) void LV;
DEV void gload_lds16(const u16* g, u16* l) {
  __builtin_amdgcn_global_load_lds((GV*)g, (LV*)l, 16, 0, 0);
}

// ---------- weight transpose: 4 D x D matrices per layer in one dispatch ----------
__global__ __launch_bounds__(256) void wprep4_kernel(const float* __restrict__ wq,
                                                     const float* __restrict__ wk,
                                                     const float* __restrict__ wv,
                                                     const float* __restrict__ wo,
                                                     u16* __restrict__ wqkvT,
                                                     u16* __restrict__ woT) {
  __shared__ float tile[32][33];
  const int z = blockIdx.z, which = z & 3, lyr = z >> 2;
  const float* in = (which == 0 ? wq : which == 1 ? wk : which == 2 ? wv : wo)
                    + (size_t)lyr * D * D;
  u16* out = (which < 3) ? wqkvT + (size_t)lyr * QKV * D + (size_t)which * D * D
                         : woT + (size_t)lyr * D * D;
  const int k0 = blockIdx.x * 32, n0 = blockIdx.y * 32;
  const int tx = (int)threadIdx.x & 31, ty = (int)threadIdx.x >> 5;
#pragma unroll
  for (int i = 0; i < 32; i += 8)
    tile[ty + i][tx] = in[(size_t)(k0 + ty + i) * D + n0 + tx];
  __syncthreads();
#pragma unroll
  for (int i = 0; i < 32; i += 8)
    out[(size_t)(n0 + ty + i) * D + k0 + tx] = f2bf(tile[tx][ty + i]);
}

// ---------- generic weight transpose: f32 [K,N] -> bf16 [N,K], grid.z = layer ----------
__global__ __launch_bounds__(256) void wprep_kernel(const float* __restrict__ in,
                                                    u16* __restrict__ out, int K, int N,
                                                    size_t ostride) {
  __shared__ float tile[32][33];
  const int zl = blockIdx.z;
  in  += (size_t)zl * K * N;
  out += (size_t)zl * ostride;
  const int k0 = blockIdx.x * 32, n0 = blockIdx.y * 32;
  const int tx = (int)threadIdx.x & 31, ty = (int)threadIdx.x >> 5;
#pragma unroll
  for (int i = 0; i < 32; i += 8)
    tile[ty + i][tx] = in[(size_t)(k0 + ty + i) * N + n0 + tx];
  __syncthreads();
#pragma unroll
  for (int i = 0; i < 32; i += 8)
    out[(size_t)(n0 + ty + i) * K + k0 + tx] = f2bf(tile[tx][ty + i]);
}

// ---------- merged small prep: bias concat | mask bias | mask flags ----------
__global__ __launch_bounds__(256) void prep_kernel(const float* __restrict__ bq,
                                                   const float* __restrict__ bk,
                                                   const float* __restrict__ bv,
                                                   const int* __restrict__ mask,
                                                   float* __restrict__ bqkv,
                                                   float* __restrict__ mb,
                                                   int* __restrict__ flags) {
  const int blk = (int)blockIdx.x;
  const int tid = (int)threadIdx.x;
  if (blk < 36) {                       // bcat: L*QKV = 9216 elements
    const int i = blk * 256 + tid;
    const int l = i / QKV, r = i % QKV;
    const float* src = (r < D) ? bq : (r < 2 * D ? bk : bv);
    bqkv[i] = src[l * D + (r & (D - 1))];
  } else if (blk < 68) {                // mbias: TOK elements
    const int i = (blk - 36) * 256 + tid;
    mb[i] = (mask[i] == 0) ? -3e38f : 0.f;
  } else if (tid < 128) {               // mflag: 128 tiles of 64 keys
    const int* m = mask + (tid >> 4) * S + (tid & 15) * 64;
    int all = 1;
#pragma unroll
    for (int j = 0; j < 64; ++j) all &= (m[j] != 0) ? 1 : 0;
    flags[tid] = all;
  }
}

// ---------- embedding + positional encoding -> bf16 (4 tokens/block) ----------
__global__ __launch_bounds__(256) void embed_kernel(const int* __restrict__ src,
                                                    const float* __restrict__ emb,
                                                    const float* __restrict__ pe,
                                                    u16* __restrict__ xb) {
  const int t = (int)blockIdx.x * 4 + ((int)threadIdx.x >> 6);
  const int c = ((int)threadIdx.x & 63) * 8;
  const int s = t & (S - 1);
  const int tok = src[t];
  const float* ep = emb + (size_t)tok * D + c;
  const float* pp = pe + (size_t)s * D + c;
  const f32x4 e0 = *(const f32x4*)ep,       e1 = *(const f32x4*)(ep + 4);
  const f32x4 p0 = *(const f32x4*)pp,       p1 = *(const f32x4*)(pp + 4);
  uint4 ob;
  ob.x = cvtpk(e0[0] + p0[0], e0[1] + p0[1]);
  ob.y = cvtpk(e0[2] + p0[2], e0[3] + p0[3]);
  ob.z = cvtpk(e1[0] + p1[0], e1[1] + p1[1]);
  ob.w = cvtpk(e1[2] + p1[2], e1[3] + p1[3]);
  *(uint4*)(xb + (size_t)t * D + c) = ob;
}

// ---------- GEMM: C[M,N] = A[M,K](bf16) @ BT[N,K](bf16)^T ----------
// Single-buffered m97 loop; bijective XCD swizzle; N-fastest (A streamed once).
// T2 conflict fix: pre-swizzled GLOBAL source, linear gload_lds dest, same-XOR
// fragment reads (r15: -53us). KSPLIT>1: bf16 partials. VMODE: V cols
// transposed to outV[B,H,DH,S]; Q cols pre-scaled by 0.125*log2(e).
// MT=2 / 1-buffer / 5-6 blocks/CU proven optimal (r13; r18: counted-vmcnt
// dbuf at 3 blocks/CU regressed -> TLP beats intra-block pipelining here).
template <int MT, int VMODE, int KSPLIT>
__global__ __launch_bounds__(256) void gemm_kernel(const u16* __restrict__ A,
                                                   const u16* __restrict__ BT,
                                                   const float* __restrict__ bias,
                                                   u16* __restrict__ outB,
                                                   u16* __restrict__ outV,
                                                   int N, int K, int relu) {
  constexpr int BM = MT * 32;
  constexpr float QSCL = 0.125f * 1.44269504089f;
  __shared__ u16 sA[BM * 64];
  __shared__ u16 sB[128 * 64];
  const int tid = (int)threadIdx.x;
  const int w = tid >> 6, l = tid & 63;
  const int wr = w >> 1, wc = w & 1;
  const int lr = l & 15, lg = l >> 4;

  const int nwg = (int)gridDim.x;
  const int bid = (int)blockIdx.x;
  const int wg  = (bid & 7) * (nwg >> 3) + (bid >> 3);
  const int nbn = N >> 7;
  int kidx = 0, rem = wg;
  if constexpr (KSPLIT > 1) {
    const int per = nwg / KSPLIT;
    kidx = wg / per;
    rem  = wg % per;
  }
  const int bm = (rem / nbn) * BM, bn = (rem % nbn) * 128;
  const int KS = K / KSPLIT;

  f32x4 acc[MT][4];
#pragma unroll
  for (int i = 0; i < MT; ++i)
#pragma unroll
    for (int j = 0; j < 4; ++j)
#pragma unroll
      for (int r = 0; r < 4; ++r) acc[i][j][r] = 0.f;

  const int srow = tid >> 3;                       // 0..31
  const int sswz = ((tid & 7) ^ (srow & 7)) * 8;   // swizzled SOURCE chunk
  const int sdst = (tid & 7) * 8;                  // linear DEST chunk
  const u16* Ag = A + (size_t)(bm + srow) * K + kidx * KS + sswz;
  const u16* Bg = BT + (size_t)(bn + srow) * K + kidx * KS + sswz;
  u16* sAd = sA + srow * 64 + sdst;
  u16* sBd = sB + srow * 64 + sdst;

  for (int kt = 0; kt < KS; kt += 64) {
    __syncthreads();
#pragma unroll
    for (int r = 0; r < BM / 32; ++r)
      gload_lds16(Ag + (size_t)(r * 32) * K + kt, sAd + r * 32 * 64);
#pragma unroll
    for (int r = 0; r < 4; ++r)
      gload_lds16(Bg + (size_t)(r * 32) * K + kt, sBd + r * 32 * 64);
    __syncthreads();
#pragma unroll
    for (int kk = 0; kk < 2; ++kk) {
      s16x8 af[MT], bfr[4];
      const int csw = ((kk * 4 + lg) ^ (lr & 7)) << 3;   // swizzled read chunk
#pragma unroll
      for (int mt = 0; mt < MT; ++mt)
        af[mt] = *(const s16x8*)&sA[(wr * MT * 16 + mt * 16 + lr) * 64 + csw];
#pragma unroll
      for (int nt = 0; nt < 4; ++nt)
        bfr[nt] = *(const s16x8*)&sB[(wc * 64 + nt * 16 + lr) * 64 + csw];
#pragma unroll
      for (int mt = 0; mt < MT; ++mt)
#pragma unroll
        for (int nt = 0; nt < 4; ++nt)
          acc[mt][nt] = mfma16(af[mt], bfr[nt], acc[mt][nt]);
    }
  }

#pragma unroll
  for (int mt = 0; mt < MT; ++mt)
#pragma unroll
    for (int nt = 0; nt < 4; ++nt) {
      const int col = bn + wc * 64 + nt * 16 + lr;
      const int row0 = bm + wr * MT * 16 + mt * 16 + lg * 4;
      if constexpr (KSPLIT > 1) {
        u16* op = outB + (size_t)kidx * TOK * N + (size_t)row0 * N + col;
        const uint32_t p01 = cvtpk(acc[mt][nt][0], acc[mt][nt][1]);
        const uint32_t p23 = cvtpk(acc[mt][nt][2], acc[mt][nt][3]);
        op[0]               = (u16)p01;
        op[N]               = (u16)(p01 >> 16);
        op[2 * (size_t)N]   = (u16)p23;
        op[3 * (size_t)N]   = (u16)(p23 >> 16);
      } else {
        const float bv = bias ? bias[col] : 0.f;
        if (VMODE && col >= 2 * D) {    // V projection -> transposed [B,H,DH,S]
          const int dcol = col - 2 * D;
          const int hh = dcol >> 6, dh = dcol & 63;
          const int bb = row0 >> 10, s = row0 & (S - 1);
          u16* vp = outV + ((size_t)((bb << 3) + hh) * DHd + dh) * S + s;
          *(uint32_t*)(vp)     = cvtpk(acc[mt][nt][0] + bv, acc[mt][nt][1] + bv);
          *(uint32_t*)(vp + 2) = cvtpk(acc[mt][nt][2] + bv, acc[mt][nt][3] + bv);
        } else {
          float v[4];
#pragma unroll
          for (int r = 0; r < 4; ++r) {
            v[r] = acc[mt][nt][r] + bv;
            if (relu) v[r] = fmaxf(v[r], 0.f);
            if (VMODE && col < D) v[r] *= QSCL;
          }
          const size_t o0 = (size_t)row0 * N + col;
          const uint32_t p01 = cvtpk(v[0], v[1]);
          const uint32_t p23 = cvtpk(v[2], v[3]);
          outB[o0]                   = (u16)p01;
          outB[o0 + N]               = (u16)(p01 >> 16);
          outB[o0 + 2 * (size_t)N]   = (u16)p23;
          outB[o0 + 3 * (size_t)N]   = (u16)(p23 >> 16);
        }
      }
    }
}

// ---------- flash attention v9: 8 waves x 32 q, dbuf K/V, dual P slabs, no max ----------
__global__ __launch_bounds__(512) void attn_kernel(const u16* __restrict__ qkv,
                                                   const u16* __restrict__ vt,
                                                   const int* __restrict__ mflags,
                                                   const float* __restrict__ mb,
                                                   u16* __restrict__ attno) {
  __shared__ u16 sK[2][KVB * 72];
  __shared__ u16 sV[2][KVB * 72];
  __shared__ u16 sP[8][2][16][72];   // per-wave, per-q-frag slab
  const int tid = (int)threadIdx.x;
  const int w = tid >> 6, l = tid & 63;
  const int lr = l & 15, lg = l >> 4;
  const int bid = (int)blockIdx.x;
  const int wg  = (bid & 7) * 32 + (bid >> 3);
  const int bh = wg >> 2, qc = wg & 3;
  const int b = bh >> 3, h = bh & 7;
  const int q0 = qc * 256 + w * 32;

  const u16* qr0 = qkv + (size_t)(b * S + q0 + lr) * QKV + h * DHd;
  const u16* qr1 = qr0 + (size_t)16 * QKV;
  const s16x8 aq0 = *(const s16x8*)(qr0 + lg * 8);
  const s16x8 aq1 = *(const s16x8*)(qr0 + 32 + lg * 8);
  const s16x8 aq2 = *(const s16x8*)(qr1 + lg * 8);
  const s16x8 aq3 = *(const s16x8*)(qr1 + 32 + lg * 8);
  const u16* kbase = qkv + D + (size_t)b * S * QKV + h * DHd;
  const u16* vbase = vt + (size_t)bh * DHd * S;
  const float* mrow0 = mb + b * S;

  s16x8 vones;
#pragma unroll
  for (int i = 0; i < 8; ++i) vones[i] = (short)0x3F80;   // bf16 1.0

  const int srow = tid >> 3;       // 0..63
  const int sc16 = tid & 7;        // 0..7
  const u16* kg = kbase + (size_t)srow * QKV + sc16 * 8;
  const u16* vg = vbase + (size_t)srow * S + sc16 * 8;
  const int soff = srow * 72 + sc16 * 8;

  // prologue: tile0 -> buf0; tile1 -> regs
  uint4 ka = *(const uint4*)kg;
  uint4 va = *(const uint4*)vg;
  *(uint4*)&sK[0][soff] = ka;
  *(uint4*)&sV[0][soff] = va;
  ka = *(const uint4*)(kg + (size_t)KVB * QKV);
  va = *(const uint4*)(vg + KVB);
  __syncthreads();

  f32x4 o[2][4], osum[2];
#pragma unroll
  for (int f = 0; f < 2; ++f) {
#pragma unroll
    for (int nt = 0; nt < 4; ++nt)
#pragma unroll
      for (int r = 0; r < 4; ++r) o[f][nt][r] = 0.f;
#pragma unroll
    for (int r = 0; r < 4; ++r) osum[f][r] = 0.f;
  }

  constexpr int NTILE = S / KVB;   // 16
  for (int t = 0; t < NTILE; ++t) {
    const int cur = t & 1;
    if (t + 1 < NTILE) {           // write staged tile t+1 (buffer t-1, reads done)
      *(uint4*)&sK[cur ^ 1][soff] = ka;
      *(uint4*)&sV[cur ^ 1][soff] = va;
    }
    if (t + 2 < NTILE) {           // issue loads for tile t+2
      ka = *(const uint4*)(kg + (size_t)(t + 2) * KVB * QKV);
      va = *(const uint4*)(vg + (t + 2) * KVB);
    }

    // swapped QK^T (Q pre-scaled -> log2-domain scores)
    f32x4 sa[2][4];
#pragma unroll
    for (int kt = 0; kt < 4; ++kt) {
      const u16* kr = &sK[cur][(kt * 16 + lr) * 72];
      const s16x8 bk0 = *(const s16x8*)(kr + lg * 8);
      const s16x8 bk1 = *(const s16x8*)(kr + 32 + lg * 8);
      f32x4 za, zb;
#pragma unroll
      for (int r = 0; r < 4; ++r) { za[r] = 0.f; zb[r] = 0.f; }
      za = mfma16(bk0, aq0, za);
      sa[0][kt] = mfma16(bk1, aq1, za);
      zb = mfma16(bk0, aq2, zb);
      sa[1][kt] = mfma16(bk1, aq3, zb);
    }

    if (!mflags[(b << 4) + t]) {   // mask add (skipped: all-valid tiles)
#pragma unroll
      for (int kt = 0; kt < 4; ++kt) {
        const f32x4 mk = *(const f32x4*)(mrow0 + t * KVB + kt * 16 + lg * 4);
#pragma unroll
        for (int r = 0; r < 4; ++r) {
          sa[0][kt][r] += mk[r];
          sa[1][kt][r] += mk[r];
        }
      }
    }

    // P = exp2(S) directly (no max); normalization cancels any shift
#pragma unroll
    for (int f = 0; f < 2; ++f)
#pragma unroll
      for (int kt = 0; kt < 4; ++kt)
#pragma unroll
        for (int r = 0; r < 4; ++r) sa[f][kt][r] = exp2f(sa[f][kt][r]);

    // pack both frags to their own slabs
#pragma unroll
    for (int f = 0; f < 2; ++f)
#pragma unroll
      for (int kt = 0; kt < 4; ++kt) {
        uint2 pk;
        pk.x = cvtpk(sa[f][kt][0], sa[f][kt][1]);
        pk.y = cvtpk(sa[f][kt][2], sa[f][kt][3]);
        *(uint2*)&sP[w][f][lr][kt * 16 + lg * 4] = pk;
      }

    // V fragments once, shared by both q-frags
    s16x8 bv[2][4];
#pragma unroll
    for (int ks = 0; ks < 2; ++ks)
#pragma unroll
      for (int nt = 0; nt < 4; ++nt)
        bv[ks][nt] = *(const s16x8*)&sV[cur][(nt * 16 + lr) * 72 + ks * 32 + lg * 8];

#pragma unroll
    for (int ks = 0; ks < 2; ++ks) {
      const s16x8 ap0 = *(const s16x8*)&sP[w][0][lr][ks * 32 + lg * 8];
      const s16x8 ap1 = *(const s16x8*)&sP[w][1][lr][ks * 32 + lg * 8];
      osum[0] = mfma16(ap0, vones, osum[0]);
      osum[1] = mfma16(ap1, vones, osum[1]);
#pragma unroll
      for (int nt = 0; nt < 4; ++nt) {
        o[0][nt] = mfma16(ap0, bv[ks][nt], o[0][nt]);
        o[1][nt] = mfma16(ap1, bv[ks][nt], o[1][nt]);
      }
    }
    __syncthreads();
  }

#pragma unroll
  for (int f = 0; f < 2; ++f) {
    float li[4];
#pragma unroll
    for (int r = 0; r < 4; ++r) li[r] = 1.f / osum[f][r];
#pragma unroll
    for (int nt = 0; nt < 4; ++nt) {
      u16* op = attno + (size_t)(b * S + q0 + f * 16 + lg * 4) * D + h * DHd + nt * 16 + lr;
#pragma unroll
      for (int r = 0; r < 4; r += 2) {
        const uint32_t pk = cvtpk(o[f][nt][r] * li[r], o[f][nt][r + 1] * li[r + 1]);
        op[(size_t)r * D]       = (u16)pk;
        op[(size_t)(r + 1) * D] = (u16)(pk >> 16);
      }
    }
  }
}

// ---------- LayerNorm over NP bf16 partials + bias + bf16 resid ----------
template <int NP>
__global__ __launch_bounds__(256) void ln_kernel(const u16* __restrict__ p,
                                                 const float* __restrict__ bias,
                                                 const u16* __restrict__ resid,
                                                 const float* __restrict__ g,
                                                 const float* __restrict__ be,
                                                 float* __restrict__ outf,   // nullable
                                                 u16* __restrict__ outb) {
  const int w = (int)threadIdx.x >> 6, l = (int)threadIdx.x & 63;
  const int t = (int)blockIdx.x * 4 + w;
  const size_t base = (size_t)t * D + l * 8;
  f32x4 v0 = *(const f32x4*)(bias + l * 8);
  f32x4 v1 = *(const f32x4*)(bias + l * 8 + 4);
  {
    const s16x8 rv = *(const s16x8*)(resid + base);
#pragma unroll
    for (int i = 0; i < 4; ++i) {
      v0[i] += bf2f((u16)rv[i]);
      v1[i] += bf2f((u16)rv[i + 4]);
    }
  }
#pragma unroll
  for (int np = 0; np < NP; ++np) {
    const s16x8 pv = *(const s16x8*)(p + (size_t)np * TOK * D + base);
#pragma unroll
    for (int i = 0; i < 4; ++i) {
      v0[i] += bf2f((u16)pv[i]);
      v1[i] += bf2f((u16)pv[i + 4]);
    }
  }
  float s = 0.f, sq = 0.f;
#pragma unroll
  for (int i = 0; i < 4; ++i) {
    s += v0[i] + v1[i];
    sq += v0[i] * v0[i] + v1[i] * v1[i];
  }
  for (int m = 1; m < 64; m <<= 1) {
    s += __shfl_xor(s, m);
    sq += __shfl_xor(sq, m);
  }
  const float mu = s * (1.0f / D);
  const float var = sq * (1.0f / D) - mu * mu;
  const float rs = rsqrtf(var + 1e-5f);
  const f32x4 g0 = *(const f32x4*)(g + l * 8);
  const f32x4 g1v = *(const f32x4*)(g + l * 8 + 4);
  const f32x4 b0 = *(const f32x4*)(be + l * 8);
  const f32x4 b1v = *(const f32x4*)(be + l * 8 + 4);
  f32x4 y0, y1;
#pragma unroll
  for (int i = 0; i < 4; ++i) {
    y0[i] = (v0[i] - mu) * rs * g0[i] + b0[i];
    y1[i] = (v1[i] - mu) * rs * g1v[i] + b1v[i];
  }
  uint4 ob;
  ob.x = cvtpk(y0[0], y0[1]);
  ob.y = cvtpk(y0[2], y0[3]);
  ob.z = cvtpk(y1[0], y1[1]);
  ob.w = cvtpk(y1[2], y1[3]);
  if (outf) {
    *(f32x4*)(outf + base) = y0;
    *(f32x4*)(outf + base + 4) = y1;
  }
  *(uint4*)(outb + base) = ob;
}

// ---------- launch ----------
extern "C" void kernel_launch(void* const* d_in, const int* in_sizes, int n_in,
                              void* d_out, int out_size, void* d_ws, size_t ws_size,
                              hipStream_t stream) {
  (void)in_sizes; (void)n_in; (void)out_size; (void)ws_size;
  const int*   src  = (const int*)d_in[0];
  const int*   mask = (const int*)d_in[1];
  const float* emb  = (const float*)d_in[2];
  const float* pe   = (const float*)d_in[3];
  const float* wq = (const float*)d_in[4];  const float* bq = (const float*)d_in[5];
  const float* wk = (const float*)d_in[6];  const float* bk = (const float*)d_in[7];
  const float* wv = (const float*)d_in[8];  const float* bv = (const float*)d_in[9];
  const float* wo = (const float*)d_in[10]; const float* bo = (const float*)d_in[11];
  const float* w1 = (const float*)d_in[12]; const float* b1 = (const float*)d_in[13];
  const float* w2 = (const float*)d_in[14]; const float* b2 = (const float*)d_in[15];
  const float* g1 = (const float*)d_in[16]; const float* be1 = (const float*)d_in[17];
  const float* g2 = (const float*)d_in[18]; const float* be2 = (const float*)d_in[19];

  char* ws = (char*)d_ws;
  size_t off = 0;
  auto alloc = [&](size_t bytes) -> void* {
    void* p = ws + off;
    off += (bytes + 255) & ~(size_t)255;
    return p;
  };

  u16* wqkvT = (u16*)alloc((size_t)L * QKV * D * 2);
  u16* woT   = (u16*)alloc((size_t)L * D * D * 2);
  u16* w1T   = (u16*)alloc((size_t)L * D * FF * 2);
  u16* w2T   = (u16*)alloc((size_t)L * D * FF * 2);
  float* bqkv = (float*)alloc((size_t)L * QKV * 4);
  float* mbf  = (float*)alloc((size_t)TOK * 4);
  int*   mflg = (int*)alloc(128 * 4);
  u16* xb    = (u16*)alloc((size_t)TOK * D * 2);   // residual / layer input (bf16)
  u16* x1b   = (u16*)alloc((size_t)TOK * D * 2);
  u16* attno = (u16*)alloc((size_t)TOK * D * 2);
  u16* qkvb  = (u16*)alloc((size_t)TOK * FF * 2);  // qkv | FFN hidden (aliased)
  u16* vtb   = (u16*)alloc((size_t)TOK * D * 2);
  u16* hbuf  = qkvb;
  u16* pf    = (u16*)alloc((size_t)2 * TOK * D * 2);  // split-K bf16 partials (NP=2)
  u16* po    = pf;

  const dim3 blk(256);

  wprep4_kernel<<<dim3(16, 16, 4 * L), blk, 0, stream>>>(wq, wk, wv, wo, wqkvT, woT);
  wprep_kernel<<<dim3(16, 64, L), blk, 0, stream>>>(w1, w1T, D, FF, (size_t)D * FF);
  wprep_kernel<<<dim3(64, 16, L), blk, 0, stream>>>(w2, w2T, FF, D, (size_t)D * FF);
  prep_kernel<<<dim3(69), blk, 0, stream>>>(bq, bk, bv, mask, bqkv, mbf, mflg);

  embed_kernel<<<TOK / 4, blk, 0, stream>>>(src, emb, pe, xb);

  for (int lyr = 0; lyr < L; ++lyr) {
    const size_t wOffQ = (size_t)lyr * QKV * D;
    const size_t wOffD = (size_t)lyr * D * D;
    const size_t wOffF = (size_t)lyr * D * FF;
    // fused QKV projection (BM=64); V transposed in-epilogue; Q pre-scaled
    gemm_kernel<2, 1, 1><<<dim3(128 * 12), blk, 0, stream>>>(xb, wqkvT + wOffQ, bqkv + lyr * QKV,
                                                             qkvb, vtb, QKV, D, 0);
    attn_kernel<<<dim3(256), dim3(512), 0, stream>>>(qkvb, vtb, mflg, mbf, attno);
    // O-projection: split-K=2 -> bf16 partials; bias+resid fused into LN1
    gemm_kernel<2, 0, 2><<<dim3(128 * 4 * 2), blk, 0, stream>>>(attno, woT + wOffD, nullptr,
                                                                po, nullptr, D, D, 0);
    ln_kernel<2><<<TOK / 4, blk, 0, stream>>>(po, bo + lyr * D, xb,
                                              g1 + lyr * D, be1 + lyr * D, nullptr, x1b);
    // FFN (BM=64)
    gemm_kernel<2, 0, 1><<<dim3(128 * 16), blk, 0, stream>>>(x1b, w1T + wOffF, b1 + lyr * FF,
                                                             hbuf, nullptr, FF, D, 1);
    gemm_kernel<2, 0, 2><<<dim3(128 * 4 * 2), blk, 0, stream>>>(hbuf, w2T + wOffF, nullptr,
                                                                pf, nullptr, D, FF, 0);
    float* xdst = (lyr == L - 1) ? (float*)d_out : nullptr;
    ln_kernel<2><<<TOK / 4, blk, 0, stream>>>(pf, b2 + lyr * D, x1b,
                                              g2 + lyr * D, be2 + lyr * D, xdst, xb);
  }
}